// Round 1
// 520.909 us; speedup vs baseline: 1.0030x; 1.0030x over previous
//
#include <hip/hip_runtime.h>
#include <cstdint>

// out = G @ (x @ W^T + b)      [8192,8192] @ [8192,128]
// mask is ignored: mask == (G==0), so where(mask,0,G) == G identically.
#define NN 8192   // nodes
#define KD 256    // in_dim
#define HD 128    // hidden

// R4: DRAM-page-locality restructure.
// Old: 64-row tiles, BK=32 (128 B per row-visit) -> 65536 concurrent
// 128B-granularity streams -> activate/precharge bound ~1.9 TB/s.
// New: 32-row tiles, BK=128 (512 B contiguous per row-visit), SPLITK=4
// (grid stays 1024, fully resident) -> 32768 streams, 4x amortization.
// ht (2 MB) is L2-resident: B-fragments read direct from global, no hsh
// staging -> LDS = 2x16 KB G only -> still 4 blocks/CU.
#define SPLITK 4
#define KS (NN / SPLITK)   // 2048 k per block
#define BK 128             // k floats per pipeline step (512 B per row)
#define NSTEP (KS / BK)    // 16 steps
#define MROWS 32           // G rows per block

typedef __attribute__((ext_vector_type(4))) float   f32x4;
typedef __attribute__((ext_vector_type(8))) __bf16  bf16x8;
typedef __attribute__((ext_vector_type(8))) unsigned short ushort8;

// fp32 -> bf16 round-to-nearest-even
static __device__ __forceinline__ unsigned short f2bf(float f) {
  unsigned u = __builtin_bit_cast(unsigned, f);
  u += 0x7FFFu + ((u >> 16) & 1u);
  return (unsigned short)(u >> 16);
}

static __device__ __forceinline__ bf16x8 pack8(const float4 a, const float4 b) {
  ushort8 u;
  u[0] = f2bf(a.x); u[1] = f2bf(a.y); u[2] = f2bf(a.z); u[3] = f2bf(a.w);
  u[4] = f2bf(b.x); u[5] = f2bf(b.y); u[6] = f2bf(b.z); u[7] = f2bf(b.w);
  return __builtin_bit_cast(bf16x8, u);
}

#define GLD_LDS16(g, l)                                                        \
  __builtin_amdgcn_global_load_lds(                                            \
      (const __attribute__((address_space(1))) void*)(g),                      \
      (__attribute__((address_space(3))) void*)(l), 16, 0, 0)

// ---------------------------------------------------------------------------
// Kernel A: ht[n][m] = sum_k x[m][k]*W[n][k] + b[n], bf16, [HD][NN].
// ---------------------------------------------------------------------------
__global__ __launch_bounds__(64) void fc_ht_kernel(
    const float* __restrict__ x, const float* __restrict__ W,
    const float* __restrict__ bias, unsigned short* __restrict__ ht)
{
  const int lane = threadIdx.x & 63;
  const int l15  = lane & 15;
  const int lq   = lane >> 4;
  const int m0   = blockIdx.x * 16;

  f32x4 acc[8];
#pragma unroll
  for (int t = 0; t < 8; ++t) acc[t] = (f32x4)0.0f;

  const float* xr = x + (size_t)(m0 + l15) * KD;
#pragma unroll 1
  for (int s = 0; s < KD / 32; ++s) {
    const int k = s * 32 + lq * 8;
    const bf16x8 af = pack8(*(const float4*)(xr + k), *(const float4*)(xr + k + 4));
#pragma unroll
    for (int t = 0; t < 8; ++t) {
      const float* wr = W + (size_t)(t * 16 + l15) * KD + k;
      const bf16x8 bfr = pack8(*(const float4*)wr, *(const float4*)(wr + 4));
      acc[t] = __builtin_amdgcn_mfma_f32_16x16x32_bf16(af, bfr, acc[t], 0, 0, 0);
    }
  }

  // C/D layout: col = lane&15, row = (lane>>4)*4 + reg.
#pragma unroll
  for (int t = 0; t < 8; ++t) {
    const int n  = t * 16 + l15;
    const float bv = bias[n];
    const int mr = m0 + lq * 4;
    uint2 v;
    v.x = (unsigned)f2bf(acc[t][0] + bv) | ((unsigned)f2bf(acc[t][1] + bv) << 16);
    v.y = (unsigned)f2bf(acc[t][2] + bv) | ((unsigned)f2bf(acc[t][3] + bv) << 16);
    *(uint2*)(ht + (size_t)n * NN + mr) = v;
  }
}

// ---------------------------------------------------------------------------
// Kernel B: 32-row x 2048-k tiles. G double-buffered in LDS (512 B/row/stage),
// ht B-frags direct from L2. Per-block K-phase rotation kept (16 phases x
// 4 ks-stripes x 512 B = full 32 KB row footprint live device-wide).
// Waves split the 128 n-cols 4x32; every wave reads both 16-row A-frags.
// XOR swizzle on the low-3 chunk bits (within each 128 B group): write side
// pre-swizzles the GLOBAL source (gld_lds dest must stay linear), read side
// applies the same XOR -> banks uniform (verified pattern from R3).
// ---------------------------------------------------------------------------
__global__ __launch_bounds__(256, 4) void spmm_kernel(
    const float* __restrict__ G, const unsigned short* __restrict__ ht,
    float* __restrict__ P)
{
  __shared__ float gsh[2][MROWS * BK];   // 16 KB per buffer

  const int tid   = threadIdx.x;
  const int lane  = tid & 63;
  const int wave  = tid >> 6;
  const int l15   = lane & 15;
  const int lq    = lane >> 4;
  const int mtile = blockIdx.x >> 2;   // 0..255
  const int ks    = blockIdx.x & 3;
  const int m0    = mtile * MROWS;
  const int kb0   = ks * KS;
  const int phase = mtile & (NSTEP - 1);

  f32x4 acc[2][2];
#pragma unroll
  for (int a = 0; a < 2; ++a)
#pragma unroll
    for (int t = 0; t < 2; ++t) acc[a][t] = (f32x4)0.0f;

  // stage = 32 rows x 512 B. 1024 lane-loads = 4 per thread. Chunk index
  // c in 0..31 (16 B units); XOR only the low 3 bits -> permutation stays
  // inside each 128 B group, source stays 512 B-contiguous per row.
#define STAGE(s_, buf_)                                                         \
  do {                                                                          \
    const int kb_ = kb0 + (((s_) + phase) & (NSTEP - 1)) * BK;                  \
    _Pragma("unroll")                                                           \
    for (int i = 0; i < 4; ++i) {                                               \
      const int e = i * 256 + tid;                                              \
      const int r = e >> 5, c = e & 31;                                         \
      GLD_LDS16(G + (size_t)(m0 + r) * NN + kb_ +                               \
                    (((c & 24) | ((c & 7) ^ (r & 7))) * 4),                     \
                &gsh[buf_][e * 4]);                                             \
    }                                                                           \
  } while (0)

  STAGE(0, 0);

  // read-side swizzled chunk offsets within a sub-step's 8-chunk window
  const int gsw0 = (lq * 2 + 0) ^ (l15 & 7);
  const int gsw1 = (lq * 2 + 1) ^ (l15 & 7);

#pragma unroll 1
  for (int s = 0; s < NSTEP; ++s) {
    const int kb = kb0 + ((s + phase) & (NSTEP - 1)) * BK;
    __syncthreads();                      // vmcnt(0) drain: buf[s&1] ready

    // B-fragments for THIS stage, issued BEFORE next STAGE so the compiler's
    // vmcnt wait for hb does not drain the s+1 prefetch (FIFO vmcnt).
    uint4 hb[4][2];
#pragma unroll
    for (int sub = 0; sub < 4; ++sub)
#pragma unroll
      for (int t = 0; t < 2; ++t) {
        const int n = wave * 32 + t * 16 + l15;
        hb[sub][t] = *(const uint4*)(ht + (size_t)n * NN + kb + sub * 32 + lq * 8);
      }

    if (s + 1 < NSTEP) STAGE(s + 1, (s + 1) & 1);

    const int b = s & 1;
#pragma unroll
    for (int sub = 0; sub < 4; ++sub) {
      bf16x8 af[2];
#pragma unroll
      for (int a = 0; a < 2; ++a) {
        const int row = a * 16 + l15;
        const float4 g0 = *(const float4*)&gsh[b][row * BK + (sub * 8 + gsw0) * 4];
        const float4 g1 = *(const float4*)&gsh[b][row * BK + (sub * 8 + gsw1) * 4];
        af[a] = pack8(g0, g1);
      }
#pragma unroll
      for (int a = 0; a < 2; ++a)
#pragma unroll
        for (int t = 0; t < 2; ++t)
          acc[a][t] = __builtin_amdgcn_mfma_f32_16x16x32_bf16(
              af[a], __builtin_bit_cast(bf16x8, hb[sub][t]), acc[a][t], 0, 0, 0);
    }
  }

  // epilogue: split-K partials, P[ks][m][n]. C/D: col=lane&15, row=lq*4+reg.
  float* __restrict__ pp = P + (size_t)ks * NN * HD;
#pragma unroll
  for (int a = 0; a < 2; ++a)
#pragma unroll
    for (int t = 0; t < 2; ++t) {
      const int n = wave * 32 + t * 16 + l15;
      const int mr = m0 + a * 16 + lq * 4;
#pragma unroll
      for (int r = 0; r < 4; ++r)
        pp[(size_t)(mr + r) * HD + n] = acc[a][t][r];
    }
}

// ---------------------------------------------------------------------------
// Kernel C: out[m][n] = sum_ks P[ks][m][n].
// ---------------------------------------------------------------------------
__global__ __launch_bounds__(256) void reduce_kernel(
    const f32x4* __restrict__ P, f32x4* __restrict__ out)
{
  const int idx = blockIdx.x * 256 + threadIdx.x;   // 0..262143 float4s
  const int S = NN * HD / 4;
  f32x4 s = P[idx];
#pragma unroll
  for (int k = 1; k < SPLITK; ++k) s += P[(size_t)k * S + idx];
  out[idx] = s;
}

extern "C" void kernel_launch(void* const* d_in, const int* in_sizes, int n_in,
                              void* d_out, int out_size, void* d_ws, size_t ws_size,
                              hipStream_t stream) {
  const float* x = (const float*)d_in[0];
  const float* G = (const float*)d_in[1];
  // d_in[2] = mask: NEVER read. mask == (G==0) => where(mask,0,G) == G.
  const float* W = (const float*)d_in[3];
  const float* b = (const float*)d_in[4];
  float* out = (float*)d_out;

  unsigned short* ht = (unsigned short*)d_ws;                  // 2 MB
  float* P = (float*)((char*)d_ws + (4u << 20));               // 16 MB partials

  fc_ht_kernel<<<NN / 16, 64, 0, stream>>>(x, W, b, ht);
  spmm_kernel<<<(NN / MROWS) * SPLITK, 256, 0, stream>>>(G, ht, P);
  reduce_kernel<<<NN * HD / 4 / 256, 256, 0, stream>>>((const f32x4*)P, (f32x4*)out);
}